// Round 1
// baseline (908.575 us; speedup 1.0000x reference)
//
#include <hip/hip_runtime.h>
#include <math.h>

#define NN 8192
#define SPARSE_WEIGHT 0.01f

// Workspace layout (floats):
// ws[0] = sum_cos, ws[1] = sum_sin, ws[2] = sum_K2, ws[3] = sum_absK
// ws[4 .. 4+NN)      = sj[j] = alive[j]*sin(phases[j])
// ws[4+NN .. 4+2NN)  = cj[j] = alive[j]*cos(phases[j])

__device__ __forceinline__ float wave_reduce_sum(float v) {
#pragma unroll
    for (int off = 32; off > 0; off >>= 1)
        v += __shfl_down(v, off, 64);
    return v;
}

// Kernel A: per-element sin/cos prep + global sums of cos/sin for R.
__global__ __launch_bounds__(256) void prep_kernel(
        const float* __restrict__ phases,
        const float* __restrict__ alive,
        float* __restrict__ sj,
        float* __restrict__ cj,
        float* __restrict__ acc) {
    int j = blockIdx.x * blockDim.x + threadIdx.x;
    float s = 0.f, c = 0.f;
    if (j < NN) {
        float p = phases[j];
        s = sinf(p);
        c = cosf(p);
        float a = alive[j];
        sj[j] = a * s;
        cj[j] = a * c;
    }
    // reduce raw sin & cos (not alive-weighted) for R
    float ws = wave_reduce_sum(s);
    float wc = wave_reduce_sum(c);
    __shared__ float red_s[4], red_c[4];
    int lane = threadIdx.x & 63;
    int wave = threadIdx.x >> 6;
    if (lane == 0) { red_s[wave] = ws; red_c[wave] = wc; }
    __syncthreads();
    if (threadIdx.x == 0) {
        float bs = red_s[0] + red_s[1] + red_s[2] + red_s[3];
        float bc = red_c[0] + red_c[1] + red_c[2] + red_c[3];
        atomicAdd(&acc[1], bs);
        atomicAdd(&acc[0], bc);
    }
}

// Kernel B: one block per row i. Stream K-row and dist-row once, fuse:
//   t1 = sum_j K*dist*sj[j],  t2 = sum_j K*dist*cj[j]
//   k2 = sum_j K*K,           ka = sum_j |K|
// dtheta[i] = alive[i] * (cos(p_i)*t1 - sin(p_i)*t2)
__global__ __launch_bounds__(256) void row_kernel(
        const float* __restrict__ K,
        const float* __restrict__ dist,
        const float* __restrict__ sj,
        const float* __restrict__ cj,
        const float* __restrict__ phases,
        const float* __restrict__ alive,
        float* __restrict__ dtheta,   // points at out+1
        float* __restrict__ acc) {
    const int i = blockIdx.x;
    const float4* __restrict__ Kr = (const float4*)(K + (size_t)i * NN);
    const float4* __restrict__ Dr = (const float4*)(dist + (size_t)i * NN);
    const float4* __restrict__ S4 = (const float4*)sj;
    const float4* __restrict__ C4 = (const float4*)cj;

    float t1 = 0.f, t2 = 0.f, k2 = 0.f, ka = 0.f;
#pragma unroll 4
    for (int q = threadIdx.x; q < NN / 4; q += 256) {
        float4 k = Kr[q];
        float4 d = Dr[q];
        float4 s = S4[q];
        float4 c = C4[q];
        float km;
        km = k.x * d.x; t1 += km * s.x; t2 += km * c.x; k2 += k.x * k.x; ka += fabsf(k.x);
        km = k.y * d.y; t1 += km * s.y; t2 += km * c.y; k2 += k.y * k.y; ka += fabsf(k.y);
        km = k.z * d.z; t1 += km * s.z; t2 += km * c.z; k2 += k.z * k.z; ka += fabsf(k.z);
        km = k.w * d.w; t1 += km * s.w; t2 += km * c.w; k2 += k.w * k.w; ka += fabsf(k.w);
    }

    t1 = wave_reduce_sum(t1);
    t2 = wave_reduce_sum(t2);
    k2 = wave_reduce_sum(k2);
    ka = wave_reduce_sum(ka);

    __shared__ float red[4][4];
    int lane = threadIdx.x & 63;
    int wave = threadIdx.x >> 6;
    if (lane == 0) { red[0][wave] = t1; red[1][wave] = t2; red[2][wave] = k2; red[3][wave] = ka; }
    __syncthreads();
    if (threadIdx.x == 0) {
        t1 = red[0][0] + red[0][1] + red[0][2] + red[0][3];
        t2 = red[1][0] + red[1][1] + red[1][2] + red[1][3];
        k2 = red[2][0] + red[2][1] + red[2][2] + red[2][3];
        ka = red[3][0] + red[3][1] + red[3][2] + red[3][3];
        float p = phases[i];
        dtheta[i] = alive[i] * (cosf(p) * t1 - sinf(p) * t2);
        atomicAdd(&acc[2], k2);
        atomicAdd(&acc[3], ka);
    }
}

// Kernel C: finalize scalars.
__global__ void finalize_kernel(const float* __restrict__ acc, float* __restrict__ out) {
    if (threadIdx.x == 0 && blockIdx.x == 0) {
        float cs = acc[0] / (float)NN;
        float ss = acc[1] / (float)NN;
        float R = sqrtf(cs * cs + ss * ss);
        out[0] = R;
        out[NN + 1] = 1.0f - R + 0.01f * sqrtf(acc[2]) + SPARSE_WEIGHT * acc[3];
    }
}

extern "C" void kernel_launch(void* const* d_in, const int* in_sizes, int n_in,
                              void* d_out, int out_size, void* d_ws, size_t ws_size,
                              hipStream_t stream) {
    const float* phases = (const float*)d_in[0];
    const float* alive  = (const float*)d_in[1];
    const float* dist   = (const float*)d_in[2];
    const float* K      = (const float*)d_in[3];
    float* out = (float*)d_out;
    float* ws  = (float*)d_ws;

    float* acc = ws;            // 4 floats
    float* sj  = ws + 4;        // NN floats (16B-aligned offset)
    float* cj  = ws + 4 + NN;   // NN floats (16B-aligned offset)

    // zero the 4 accumulators (ws is re-poisoned 0xAA before every launch)
    hipMemsetAsync(acc, 0, 4 * sizeof(float), stream);

    prep_kernel<<<NN / 256, 256, 0, stream>>>(phases, alive, sj, cj, acc);
    row_kernel<<<NN, 256, 0, stream>>>(K, dist, sj, cj, phases, alive, out + 1, acc);
    finalize_kernel<<<1, 64, 0, stream>>>(acc, out);
}